// Round 3
// baseline (429.107 us; speedup 1.0000x reference)
//
#include <hip/hip_runtime.h>
#include <hip/hip_fp16.h>
#include <hip/hip_cooperative_groups.h>
#include <stdint.h>

namespace cg = cooperative_groups;

#define O_FEAT 4096
#define I_FEAT 4096
#define M_DIM  2048
#define K_DIM  4096

typedef __attribute__((ext_vector_type(8))) short short8;   // 8 x bf16 (4 VGPRs)
typedef __attribute__((ext_vector_type(2))) short short2v;  // 2 x bf16 (1 VGPR)
typedef __attribute__((ext_vector_type(4))) float floatx4;  // MFMA accumulator

#define AS1 __attribute__((address_space(1)))
#define AS3 __attribute__((address_space(3)))

__device__ __forceinline__ uint16_t f32_to_bf16(float f) {
    uint32_t u = __builtin_bit_cast(uint32_t, f);
    u = (u + 0x7FFFu + ((u >> 16) & 1u)) >> 16;   // round-to-nearest-even
    return (uint16_t)u;
}
__device__ __forceinline__ float bf16_to_f32(uint16_t h) {
    uint32_t u = ((uint32_t)h) << 16;
    return __builtin_bit_cast(float, u);
}

// async global->LDS, 16B per lane; LDS dest = wave-uniform base + lane*16
__device__ __forceinline__ void load_lds16(const uint16_t* gptr, uint16_t* ldsptr) {
    __builtin_amdgcn_global_load_lds((const AS1 uint32_t*)gptr,
                                     (AS3 uint32_t*)ldsptr, 16, 0, 0);
}

// ---------------------------------------------------------------------------
// R11: ONE cooperative kernel.  256 blocks x 512 threads (1 block/CU,
// co-resident).  Phase 1: dequant int4->bf16 W + x->bf16 Xb.  grid.sync().
// Phase 2: scatter COO residual into W (bf16-pair atomic).  grid.sync().
// Phase 3: GEMM — R9-EXACT structure (4 thin phases/K-tile, T1+T2 swizzle,
// counted vmcnt(6), 3-buffer depth-2 prefetch, setprio): 74.6 us / 37.5%
// MfmaUtil proven; R10 fat-phase (2x16 MFMA) regressed to 77.5 — thin phases
// let the 2 waves/SIMD slip half-a-phase so reads hide under MFMA.
// Fusion removes 2 launch/drain boundaries and makes the whole pipeline one
// dispatch -> counters finally attribute the ~153 us non-GEMM mystery.
// ---------------------------------------------------------------------------
#define BM 128
#define BN 256
#define BK 64
#define NT (K_DIM / BK)                 // 64
#define A_ELEMS (BM * BK)               // 8192
#define B_ELEMS (BN * BK)               // 16384
#define TILE_ELEMS (A_ELEMS + B_ELEMS)  // 24576 elems = 48 KiB

#define NTHREADS 131072                 // 256 * 512

#define MFMA16(d, a, b) d = __builtin_amdgcn_mfma_f32_16x16x32_bf16(a, b, d, 0, 0, 0)

__global__ __launch_bounds__(512, 2) void fused_kernel(
        const void*  __restrict__ packed,
        const float* __restrict__ scales,
        const float* __restrict__ x,
        const void*  __restrict__ vals,
        const int*   __restrict__ rows,
        const int*   __restrict__ cols,
        const float* __restrict__ alpha,
        uint16_t*    __restrict__ W,
        uint16_t*    __restrict__ Xb,
        float*       __restrict__ C,
        int nnz) {
    __shared__ uint16_t lds[3 * TILE_ELEMS];   // 144 KiB (phase 3 only)

    cg::grid_group grid = cg::this_grid();
    const int tid  = threadIdx.x;
    const int lane = tid & 63;
    const int gid  = blockIdx.x * 512 + tid;        // 0..131071

    // ================= phase 1: dequant W + xconv Xb =================
    {
        uint32_t probe = ((const uint32_t*)packed)[lane];
        const bool int32mode = (__ballot(probe >= 256u) == 0ull);
#pragma unroll
        for (int it = 0; it < 16; ++it) {           // 2,097,152 quad-units
            const int idx = it * NTHREADS + gid;
            const float s = scales[idx >> 9];       // 512 byte-quads per row
            uint32_t bytes4;
            if (int32mode) {
                uint4 w = ((const uint4*)packed)[idx];
                bytes4 = (w.x & 0xFFu) | ((w.y & 0xFFu) << 8) |
                         ((w.z & 0xFFu) << 16) | ((w.w & 0xFFu) << 24);
            } else {
                bytes4 = ((const uint32_t*)packed)[idx];
            }
            uint16_t o[8];
#pragma unroll
            for (int b = 0; b < 4; ++b) {
                int byte = (bytes4 >> (8 * b)) & 0xFF;
                o[2 * b]     = f32_to_bf16((float)((byte & 0xF) - 8) * s);  // low -> even
                o[2 * b + 1] = f32_to_bf16((float)((byte >> 4) - 8) * s);   // high -> odd
            }
            uint4 v;
            v.x = (uint32_t)o[0] | ((uint32_t)o[1] << 16);
            v.y = (uint32_t)o[2] | ((uint32_t)o[3] << 16);
            v.z = (uint32_t)o[4] | ((uint32_t)o[5] << 16);
            v.w = (uint32_t)o[6] | ((uint32_t)o[7] << 16);
            ((uint4*)W)[idx] = v;
        }
#pragma unroll
        for (int it = 0; it < 8; ++it) {            // 1,048,576 float8-units
            const int idx = it * NTHREADS + gid;
            float4 v0 = ((const float4*)x)[2 * idx];
            float4 v1 = ((const float4*)x)[2 * idx + 1];
            uint4 o;
            o.x = (uint32_t)f32_to_bf16(v0.x) | ((uint32_t)f32_to_bf16(v0.y) << 16);
            o.y = (uint32_t)f32_to_bf16(v0.z) | ((uint32_t)f32_to_bf16(v0.w) << 16);
            o.z = (uint32_t)f32_to_bf16(v1.x) | ((uint32_t)f32_to_bf16(v1.y) << 16);
            o.w = (uint32_t)f32_to_bf16(v1.z) | ((uint32_t)f32_to_bf16(v1.w) << 16);
            ((uint4*)Xb)[idx] = o;
        }
    }
    __threadfence();
    grid.sync();

    // ================= phase 2: scatter residual into W =================
    {
        float p = fabsf(((const float*)vals)[lane]);
        int cnt = __popcll(__ballot(p > 1e-4f && p < 1.0f));
        const bool f32mode = (cnt >= 32);
        const float al = alpha[0];
#pragma unroll
        for (int it = 0; it < 7; ++it) {            // 7*131072 >= 838860
            const int i = it * NTHREADS + gid;
            if (i < nnz) {
                float v = f32mode ? ((const float*)vals)[i]
                                  : __half2float(((const __half*)vals)[i]);
                v *= al;
                int r = rows[i], c = cols[i];
                size_t elem = (size_t)r * I_FEAT + c;
#if __has_builtin(__builtin_amdgcn_global_atomic_fadd_v2bf16)
                const bool hi = (elem & 1);
                short b = (short)f32_to_bf16(v);
                short2v val;
                val[0] = hi ? (short)0 : b;
                val[1] = hi ? b : (short)0;
                __builtin_amdgcn_global_atomic_fadd_v2bf16(
                    (AS1 short2v*)(W + (elem & ~(size_t)1)), val);
#else
                uint32_t* word = (uint32_t*)W + (elem >> 1);
                bool hi = (c & 1);
                uint32_t old = *word, assumed;
                do {
                    assumed = old;
                    uint16_t cur = hi ? (uint16_t)(assumed >> 16)
                                      : (uint16_t)(assumed & 0xFFFF);
                    uint16_t nw  = f32_to_bf16(bf16_to_f32(cur) + v);
                    uint32_t neww = hi ? ((assumed & 0x0000FFFFu) | ((uint32_t)nw << 16))
                                       : ((assumed & 0xFFFF0000u) | (uint32_t)nw);
                    old = atomicCAS(word, assumed, neww);
                } while (old != assumed);
#endif
            }
        }
    }
    __threadfence();
    grid.sync();

    // ================= phase 3: GEMM (R9-exact) =================
    const uint16_t* __restrict__ A = Xb;            // [2048][4096] bf16
    const uint16_t* __restrict__ B = W;             // [4096][4096] bf16 [N][K]

    const int wave = tid >> 6;
    const int wm   = wave >> 2;          // 0..1  (64 rows each)
    const int wn   = wave & 3;           // 0..3  (64 cols each)

    // XCD-aware bijective block swizzle: 256 blocks, 8 XCDs (256 % 8 == 0)
    const int wgid = blockIdx.x;
    const int swz  = (wgid & 7) * 32 + (wgid >> 3);
    const int bm0  = (swz >> 4) * BM;
    const int bn0  = (swz & 15) * BN;

    // ---- staging addresses: thread -> 16B slot, source pre-swizzled ----
    // slot (r,q) sources global k-quad (q ^ (r&7));  r&7 == lane>>3.
    const int srow = (wave << 3) + (lane >> 3);              // 0..63
    const int xcol = ((lane & 7) ^ (lane >> 3)) << 3;        // swizzled k-elem
    const uint16_t* gA0 = A + (size_t)(bm0 + srow) * K_DIM + xcol;
    const uint16_t* gA1 = gA0 + (size_t)64 * K_DIM;
    const uint16_t* gB0 = B + (size_t)(bn0 + srow) * K_DIM + xcol;
    const uint16_t* gB1 = gB0 + (size_t)64  * K_DIM;
    const uint16_t* gB2 = gB0 + (size_t)128 * K_DIM;
    const uint16_t* gB3 = gB0 + (size_t)192 * K_DIM;
    const int ldsA0 = wave * 512;
    const int ldsA1 = 4096 + wave * 512;
    const int ldsB0 = A_ELEMS + wave * 512;
    const int ldsB1 = A_ELEMS + 4096 + wave * 512;
    const int ldsB2 = A_ELEMS + 8192 + wave * 512;
    const int ldsB3 = A_ELEMS + 12288 + wave * 512;

    // ---- LDS read addressing (swizzle matches staging; conflict-free) ----
    const int fr  = lane & 15;                  // fragment row
    const int ko  = (lane >> 4) << 3;           // fragment k offset in 32-slice
    const int sk0 = (ko)      ^ ((fr & 7) << 3);
    const int sk1 = (32 + ko) ^ ((fr & 7) << 3);
    const int raA = (wm * 64 + fr) * BK;                 // + i*1024
    const int raB = A_ELEMS + (wn * 64 + fr) * BK;       // + j*1024

    floatx4 acc[4][4];
#pragma unroll
    for (int i = 0; i < 4; ++i)
#pragma unroll
        for (int j = 0; j < 4; ++j) acc[i][j] = {0.f, 0.f, 0.f, 0.f};

    // ---- prologue: stage tile0 -> buf0, tile1 -> buf1 (6 loads each) ----
    load_lds16(gA0, &lds[ldsA0]);
    load_lds16(gA1, &lds[ldsA1]);
    load_lds16(gB0, &lds[ldsB0]);
    load_lds16(gB1, &lds[ldsB1]);
    load_lds16(gB2, &lds[ldsB2]);
    load_lds16(gB3, &lds[ldsB3]);
    load_lds16(gA0 + BK, &lds[TILE_ELEMS + ldsA0]);
    load_lds16(gA1 + BK, &lds[TILE_ELEMS + ldsA1]);
    load_lds16(gB0 + BK, &lds[TILE_ELEMS + ldsB0]);
    load_lds16(gB1 + BK, &lds[TILE_ELEMS + ldsB1]);
    load_lds16(gB2 + BK, &lds[TILE_ELEMS + ldsB2]);
    load_lds16(gB3 + BK, &lds[TILE_ELEMS + ldsB3]);
    asm volatile("s_waitcnt vmcnt(6)" ::: "memory");   // tile0 landed
    __builtin_amdgcn_s_barrier();

    int cbo = 0;                 // compute buffer (tile t)   : buffer t%3
    int sbo = 2 * TILE_ELEMS;    // stage buffer (tile t+2)   : buffer (t+2)%3

    for (int t = 0; t < NT; ++t) {
        const bool pf   = (t + 2 < NT);
        const int  kofs = (t + 2) * BK;

        // ---------------- phase 0: read A0,A1 + B0,B1; stage A(t+2) ----------
        short8 a00 = *(const short8*)&lds[cbo + raA + sk0];
        short8 a01 = *(const short8*)&lds[cbo + raA + sk1];
        short8 a10 = *(const short8*)&lds[cbo + raA + 1024 + sk0];
        short8 a11 = *(const short8*)&lds[cbo + raA + 1024 + sk1];
        short8 b00 = *(const short8*)&lds[cbo + raB + sk0];
        short8 b01 = *(const short8*)&lds[cbo + raB + sk1];
        short8 b10 = *(const short8*)&lds[cbo + raB + 1024 + sk0];
        short8 b11 = *(const short8*)&lds[cbo + raB + 1024 + sk1];
        if (pf) {
            load_lds16(gA0 + kofs, &lds[sbo + ldsA0]);
            load_lds16(gA1 + kofs, &lds[sbo + ldsA1]);
        }
        __builtin_amdgcn_s_barrier();
        asm volatile("s_waitcnt lgkmcnt(0)");
        __builtin_amdgcn_s_setprio(1);
        MFMA16(acc[0][0], a00, b00); MFMA16(acc[0][0], a01, b01);
        MFMA16(acc[0][1], a00, b10); MFMA16(acc[0][1], a01, b11);
        MFMA16(acc[1][0], a10, b00); MFMA16(acc[1][0], a11, b01);
        MFMA16(acc[1][1], a10, b10); MFMA16(acc[1][1], a11, b11);
        __builtin_amdgcn_s_setprio(0);
        __builtin_amdgcn_s_barrier();

        // ---------------- phase 1: read B2,B3; stage B01(t+2) ----------------
        short8 b20 = *(const short8*)&lds[cbo + raB + 2048 + sk0];
        short8 b21 = *(const short8*)&lds[cbo + raB + 2048 + sk1];
        short8 b30 = *(const short8*)&lds[cbo + raB + 3072 + sk0];
        short8 b31 = *(const short8*)&lds[cbo + raB + 3072 + sk1];
        if (pf) {
            load_lds16(gB0 + kofs, &lds[sbo + ldsB0]);
            load_lds16(gB1 + kofs, &lds[sbo + ldsB1]);
        }
        __builtin_amdgcn_s_barrier();
        asm volatile("s_waitcnt lgkmcnt(0)");
        __builtin_amdgcn_s_setprio(1);
        MFMA16(acc[0][2], a00, b20); MFMA16(acc[0][2], a01, b21);
        MFMA16(acc[0][3], a00, b30); MFMA16(acc[0][3], a01, b31);
        MFMA16(acc[1][2], a10, b20); MFMA16(acc[1][2], a11, b21);
        MFMA16(acc[1][3], a10, b30); MFMA16(acc[1][3], a11, b31);
        __builtin_amdgcn_s_setprio(0);
        __builtin_amdgcn_s_barrier();

        // ---------------- phase 2: read A2,A3; stage B23(t+2) ----------------
        short8 a20 = *(const short8*)&lds[cbo + raA + 2048 + sk0];
        short8 a21 = *(const short8*)&lds[cbo + raA + 2048 + sk1];
        short8 a30 = *(const short8*)&lds[cbo + raA + 3072 + sk0];
        short8 a31 = *(const short8*)&lds[cbo + raA + 3072 + sk1];
        if (pf) {
            load_lds16(gB2 + kofs, &lds[sbo + ldsB2]);
            load_lds16(gB3 + kofs, &lds[sbo + ldsB3]);
        }
        __builtin_amdgcn_s_barrier();
        asm volatile("s_waitcnt lgkmcnt(0)");
        __builtin_amdgcn_s_setprio(1);
        MFMA16(acc[2][2], a20, b20); MFMA16(acc[2][2], a21, b21);
        MFMA16(acc[2][3], a20, b30); MFMA16(acc[2][3], a21, b31);
        MFMA16(acc[3][2], a30, b20); MFMA16(acc[3][2], a31, b21);
        MFMA16(acc[3][3], a30, b30); MFMA16(acc[3][3], a31, b31);
        __builtin_amdgcn_s_setprio(0);
        __builtin_amdgcn_s_barrier();

        // ---------------- phase 3: reuse regs; counted vmcnt; tile barrier ---
        __builtin_amdgcn_s_setprio(1);
        MFMA16(acc[2][0], a20, b00); MFMA16(acc[2][0], a21, b01);
        MFMA16(acc[2][1], a20, b10); MFMA16(acc[2][1], a21, b11);
        MFMA16(acc[3][0], a30, b00); MFMA16(acc[3][0], a31, b01);
        MFMA16(acc[3][1], a30, b10); MFMA16(acc[3][1], a31, b11);
        __builtin_amdgcn_s_setprio(0);
        if (t + 2 < NT) {
            // outstanding: tile t+1 (6, oldest) + tile t+2 (6) -> drain t+1
            asm volatile("s_waitcnt vmcnt(6)" ::: "memory");
        } else if (t + 1 < NT) {
            // t == NT-2: only tile NT-1's 6 loads outstanding -> drain all
            asm volatile("s_waitcnt vmcnt(0)" ::: "memory");
        }
        if (t + 1 < NT) __builtin_amdgcn_s_barrier();

        cbo += TILE_ELEMS; if (cbo == 3 * TILE_ELEMS) cbo = 0;
        sbo += TILE_ELEMS; if (sbo == 3 * TILE_ELEMS) sbo = 0;
    }

    // epilogue: C/D layout col=lane&15, row=(lane>>4)*4+reg   [m89/m91]
    const int cn  = lane & 15;
    const int rb4 = (lane >> 4) * 4;
#pragma unroll
    for (int i = 0; i < 4; ++i)
#pragma unroll
        for (int j = 0; j < 4; ++j)
#pragma unroll
            for (int r = 0; r < 4; ++r) {
                const int row = bm0 + wm * 64 + i * 16 + rb4 + r;
                const int col = bn0 + wn * 64 + j * 16 + cn;
                C[(size_t)row * O_FEAT + col] = acc[i][j][r];
            }
}

// ---------------------------------------------------------------------------
extern "C" void kernel_launch(void* const* d_in, const int* in_sizes, int n_in,
                              void* d_out, int out_size, void* d_ws, size_t ws_size,
                              hipStream_t stream) {
    const void*  packed = d_in[1];
    const float* scales = (const float*)d_in[2];
    const float* x      = (const float*)d_in[0];
    const void*  vals   = d_in[3];
    const int*   rows   = (const int*)d_in[4];
    const int*   cols   = (const int*)d_in[5];
    const float* alpha  = (const float*)d_in[6];
    float*       out    = (float*)d_out;
    int          nnz    = in_sizes[3];

    uint16_t* W  = (uint16_t*)d_ws;                                        // 32 MB
    uint16_t* Xb = (uint16_t*)((char*)d_ws + (size_t)O_FEAT * I_FEAT * 2); // 16 MB

    void* args[] = {
        (void*)&packed, (void*)&scales, (void*)&x, (void*)&vals,
        (void*)&rows, (void*)&cols, (void*)&alpha,
        (void*)&W, (void*)&Xb, (void*)&out, (void*)&nnz
    };
    hipLaunchCooperativeKernel((const void*)fused_kernel, dim3(256), dim3(512),
                               args, 0, stream);
}

// Round 4
// 305.019 us; speedup vs baseline: 1.4068x; 1.4068x over previous
//
#include <hip/hip_runtime.h>
#include <hip/hip_fp16.h>
#include <stdint.h>

#define O_FEAT 4096
#define I_FEAT 4096
#define M_DIM  2048
#define K_DIM  4096

typedef __attribute__((ext_vector_type(8))) short short8;   // 8 x bf16 (4 VGPRs)
typedef __attribute__((ext_vector_type(2))) short short2v;  // 2 x bf16 (1 VGPR)
typedef __attribute__((ext_vector_type(4))) float floatx4;  // MFMA accumulator

#define AS1 __attribute__((address_space(1)))
#define AS3 __attribute__((address_space(3)))

__device__ __forceinline__ uint16_t f32_to_bf16(float f) {
    uint32_t u = __builtin_bit_cast(uint32_t, f);
    u = (u + 0x7FFFu + ((u >> 16) & 1u)) >> 16;   // round-to-nearest-even
    return (uint16_t)u;
}
__device__ __forceinline__ float bf16_to_f32(uint16_t h) {
    uint32_t u = ((uint32_t)h) << 16;
    return __builtin_bit_cast(float, u);
}

// async global->LDS, 16B per lane; LDS dest = wave-uniform base + lane*16
__device__ __forceinline__ void load_lds16(const uint16_t* gptr, uint16_t* ldsptr) {
    __builtin_amdgcn_global_load_lds((const AS1 uint32_t*)gptr,
                                     (AS3 uint32_t*)ldsptr, 16, 0, 0);
}

// ---------------------------------------------------------------------------
// Kernel 1: dequant int4 -> bf16 W.  (R1-exact; high occupancy, BW-bound)
// R11 lesson: fusing this into the 1-block/CU GEMM kernel cut occupancy to
// 8 waves/CU and ran at 0.9 TB/s — small kernels NEED their own fat grids.
// ---------------------------------------------------------------------------
__global__ __launch_bounds__(256) void dequant_kernel(
        const void*  __restrict__ packed,
        const float* __restrict__ scales,
        uint16_t*    __restrict__ W) {
    const int lane = threadIdx.x & 63;
    uint32_t probe = ((const uint32_t*)packed)[lane];
    const bool int32mode = (__ballot(probe >= 256u) == 0ull);

    int idx = blockIdx.x * 256 + threadIdx.x;       // 2,097,152 threads
    float s = scales[idx >> 9];                     // 512 byte-quads per row

    uint32_t bytes4;
    if (int32mode) {
        uint4 w = ((const uint4*)packed)[idx];      // 4 int32, each 0..255
        bytes4 = (w.x & 0xFFu) | ((w.y & 0xFFu) << 8) |
                 ((w.z & 0xFFu) << 16) | ((w.w & 0xFFu) << 24);
    } else {
        bytes4 = ((const uint32_t*)packed)[idx];
    }

    uint16_t o[8];
#pragma unroll
    for (int b = 0; b < 4; ++b) {
        int byte = (bytes4 >> (8 * b)) & 0xFF;
        o[2 * b]     = f32_to_bf16((float)((byte & 0xF) - 8) * s);  // low -> even
        o[2 * b + 1] = f32_to_bf16((float)((byte >> 4) - 8) * s);   // high -> odd
    }
    uint4 v;
    v.x = (uint32_t)o[0] | ((uint32_t)o[1] << 16);
    v.y = (uint32_t)o[2] | ((uint32_t)o[3] << 16);
    v.z = (uint32_t)o[4] | ((uint32_t)o[5] << 16);
    v.w = (uint32_t)o[6] | ((uint32_t)o[7] << 16);
    ((uint4*)W)[idx] = v;
}

// ---------------------------------------------------------------------------
// Kernel 2 (fused): scatter COO residual into W (blocks < 3328) + x -> bf16
// (rest).  (R1-exact.)
// ---------------------------------------------------------------------------
#define SCATTER_BLOCKS 3328
__global__ __launch_bounds__(256) void scatter_xconv_kernel(
        const void*  __restrict__ vals,
        const int*   __restrict__ rows,
        const int*   __restrict__ cols,
        const float* __restrict__ alpha,
        const float* __restrict__ x,
        uint16_t*    __restrict__ W,
        uint16_t*    __restrict__ Xb,
        int nnz) {
    if (blockIdx.x < SCATTER_BLOCKS) {
        const int lane = threadIdx.x & 63;
        float p = fabsf(((const float*)vals)[lane]);
        int cnt = __popcll(__ballot(p > 1e-4f && p < 1.0f));
        const bool f32mode = (cnt >= 32);

        int i = blockIdx.x * 256 + threadIdx.x;
        if (i >= nnz) return;
        float v = f32mode ? ((const float*)vals)[i]
                          : __half2float(((const __half*)vals)[i]);
        v *= alpha[0];
        int r = rows[i], c = cols[i];
        size_t elem = (size_t)r * I_FEAT + c;

#if __has_builtin(__builtin_amdgcn_global_atomic_fadd_v2bf16)
        const bool hi = (elem & 1);
        short b = (short)f32_to_bf16(v);
        short2v val;
        val[0] = hi ? (short)0 : b;
        val[1] = hi ? b : (short)0;
        __builtin_amdgcn_global_atomic_fadd_v2bf16(
            (AS1 short2v*)(W + (elem & ~(size_t)1)), val);
#else
        uint32_t* word = (uint32_t*)W + (elem >> 1);
        bool hi = (c & 1);
        uint32_t old = *word, assumed;
        do {
            assumed = old;
            uint16_t cur = hi ? (uint16_t)(assumed >> 16) : (uint16_t)(assumed & 0xFFFF);
            uint16_t nw  = f32_to_bf16(bf16_to_f32(cur) + v);
            uint32_t neww = hi ? ((assumed & 0x0000FFFFu) | ((uint32_t)nw << 16))
                               : ((assumed & 0xFFFF0000u) | (uint32_t)nw);
            old = atomicCAS(word, assumed, neww);
        } while (old != assumed);
#endif
    } else {
        int idx = (blockIdx.x - SCATTER_BLOCKS) * 256 + threadIdx.x;  // 1,048,576
        float4 v0 = ((const float4*)x)[2 * idx];
        float4 v1 = ((const float4*)x)[2 * idx + 1];
        uint4 o;
        o.x = (uint32_t)f32_to_bf16(v0.x) | ((uint32_t)f32_to_bf16(v0.y) << 16);
        o.y = (uint32_t)f32_to_bf16(v0.z) | ((uint32_t)f32_to_bf16(v0.w) << 16);
        o.z = (uint32_t)f32_to_bf16(v1.x) | ((uint32_t)f32_to_bf16(v1.y) << 16);
        o.w = (uint32_t)f32_to_bf16(v1.z) | ((uint32_t)f32_to_bf16(v1.w) << 16);
        ((uint4*)Xb)[idx] = o;
    }
}

// ---------------------------------------------------------------------------
// Kernel 3: C[M,N] = A[M,K] * B[N,K]^T  (bf16 in, fp32 out).
// R12: B-fragments DIRECT FROM GLOBAL (L2-served), A stays LDS-staged.
// Rationale (R9 counters): at 74.6us the LDS port was the binding resource
// (reads 1170cyc + stage-writes 430 > MFMA 1242 cyc/tile/CU).  Moving B off
// LDS: LDS/tile = A 64KB reads + 16KB writes ~ 714 cyc < MFMA 1242 ->
// MFMA-bound.  B L2 traffic = 64KB/tile/CU ~ 21 TB/s < 34.5 TB/s ceiling.
// Schedule: ONE barrier + counted vmcnt(10) per K-tile (never 0 mid-loop);
// per tile issue [2x A-stage(t+2), 8x B-frag(t+2)]; B regs double-buffered
// via 2-unrolled loop (static indexing).  A staging/swizzle, fragment
// mapping, epilogue: bit-identical to the passing R9.
// ---------------------------------------------------------------------------
#define BM 128
#define BN 256
#define BK 64
#define NT (K_DIM / BK)                 // 64
#define TILE_A (BM * BK)                // 8192 elems = 16 KiB

#define MFMA16(d, a, b) d = __builtin_amdgcn_mfma_f32_16x16x32_bf16(a, b, d, 0, 0, 0)

// one K-tile: consume BF (loaded 2 tiles ago), reload BF for tile tt+2
#define GTILE(BF, tt, cbo_, sbo_)                                             \
    {                                                                         \
        short8 a00 = *(const short8*)&lds[(cbo_) + raA + sk0];                \
        short8 a01 = *(const short8*)&lds[(cbo_) + raA + sk1];                \
        short8 a10 = *(const short8*)&lds[(cbo_) + raA + 1024 + sk0];         \
        short8 a11 = *(const short8*)&lds[(cbo_) + raA + 1024 + sk1];         \
        short8 a20 = *(const short8*)&lds[(cbo_) + raA + 2048 + sk0];         \
        short8 a21 = *(const short8*)&lds[(cbo_) + raA + 2048 + sk1];         \
        short8 a30 = *(const short8*)&lds[(cbo_) + raA + 3072 + sk0];         \
        short8 a31 = *(const short8*)&lds[(cbo_) + raA + 3072 + sk1];         \
        if ((tt) + 2 < NT) {                                                  \
            const int kof = ((tt) + 2) * BK;                                  \
            load_lds16(gA0 + kof, &lds[(sbo_) + ldsA0]);                      \
            load_lds16(gA1 + kof, &lds[(sbo_) + ldsA1]);                      \
        }                                                                     \
        asm volatile("s_waitcnt lgkmcnt(0)");                                 \
        __builtin_amdgcn_s_setprio(1);                                        \
        MFMA16(acc[0][0], a00, BF[0][0]); MFMA16(acc[0][0], a01, BF[0][1]);   \
        MFMA16(acc[0][1], a00, BF[1][0]); MFMA16(acc[0][1], a01, BF[1][1]);   \
        MFMA16(acc[0][2], a00, BF[2][0]); MFMA16(acc[0][2], a01, BF[2][1]);   \
        MFMA16(acc[0][3], a00, BF[3][0]); MFMA16(acc[0][3], a01, BF[3][1]);   \
        MFMA16(acc[1][0], a10, BF[0][0]); MFMA16(acc[1][0], a11, BF[0][1]);   \
        MFMA16(acc[1][1], a10, BF[1][0]); MFMA16(acc[1][1], a11, BF[1][1]);   \
        MFMA16(acc[1][2], a10, BF[2][0]); MFMA16(acc[1][2], a11, BF[2][1]);   \
        MFMA16(acc[1][3], a10, BF[3][0]); MFMA16(acc[1][3], a11, BF[3][1]);   \
        MFMA16(acc[2][0], a20, BF[0][0]); MFMA16(acc[2][0], a21, BF[0][1]);   \
        MFMA16(acc[2][1], a20, BF[1][0]); MFMA16(acc[2][1], a21, BF[1][1]);   \
        MFMA16(acc[2][2], a20, BF[2][0]); MFMA16(acc[2][2], a21, BF[2][1]);   \
        MFMA16(acc[2][3], a20, BF[3][0]); MFMA16(acc[2][3], a21, BF[3][1]);   \
        MFMA16(acc[3][0], a30, BF[0][0]); MFMA16(acc[3][0], a31, BF[0][1]);   \
        MFMA16(acc[3][1], a30, BF[1][0]); MFMA16(acc[3][1], a31, BF[1][1]);   \
        MFMA16(acc[3][2], a30, BF[2][0]); MFMA16(acc[3][2], a31, BF[2][1]);   \
        MFMA16(acc[3][3], a30, BF[3][0]); MFMA16(acc[3][3], a31, BF[3][1]);   \
        __builtin_amdgcn_s_setprio(0);                                        \
        if ((tt) + 2 < NT) {                                                  \
            const int kof2 = ((tt) + 2) * BK;                                 \
            BF[0][0] = *(const short8*)(bp0 + kof2);                          \
            BF[0][1] = *(const short8*)(bp0 + kof2 + 32);                     \
            BF[1][0] = *(const short8*)(bp1 + kof2);                          \
            BF[1][1] = *(const short8*)(bp1 + kof2 + 32);                     \
            BF[2][0] = *(const short8*)(bp2 + kof2);                          \
            BF[2][1] = *(const short8*)(bp2 + kof2 + 32);                     \
            BF[3][0] = *(const short8*)(bp3 + kof2);                          \
            BF[3][1] = *(const short8*)(bp3 + kof2 + 32);                     \
            /* outstanding: t+1's 10 (oldest) + t+2's 10 -> drain t+1 only */ \
            asm volatile("s_waitcnt vmcnt(10)" ::: "memory");                 \
        } else if ((tt) + 1 < NT) {                                           \
            asm volatile("s_waitcnt vmcnt(0)" ::: "memory");                  \
        }                                                                     \
        if ((tt) + 1 < NT) __builtin_amdgcn_s_barrier();                      \
    }

__global__ __launch_bounds__(512, 2) void gemm_bt_kernel(
        const uint16_t* __restrict__ A,   // [2048][4096] bf16
        const uint16_t* __restrict__ B,   // [4096][4096] bf16 (row-major [N][K])
        float* __restrict__ C) {          // [2048][4096] fp32
    __shared__ uint16_t lds[3 * TILE_A];   // 48 KiB, 3 rotating A-buffers

    const int tid  = threadIdx.x;
    const int wave = tid >> 6;
    const int lane = tid & 63;
    const int wm   = wave >> 2;          // 0..1  (64 rows each)
    const int wn   = wave & 3;           // 0..3  (64 cols each)

    // XCD-aware bijective block swizzle: 256 blocks, 8 XCDs (256 % 8 == 0)
    const int wgid = blockIdx.y * 16 + blockIdx.x;
    const int swz  = (wgid & 7) * 32 + (wgid >> 3);
    const int bm0  = (swz >> 4) * BM;
    const int bn0  = (swz & 15) * BN;

    // ---- A staging (R9-exact): pre-swizzled source, linear LDS dest ----
    const int srow = (wave << 3) + (lane >> 3);              // 0..63
    const int xcol = ((lane & 7) ^ (lane >> 3)) << 3;        // swizzled k-elem
    const uint16_t* gA0 = A + (size_t)(bm0 + srow) * K_DIM + xcol;
    const uint16_t* gA1 = gA0 + (size_t)64 * K_DIM;
    const int ldsA0 = wave * 512;
    const int ldsA1 = 4096 + wave * 512;

    // ---- fragment addressing (R9-exact) ----
    const int fr  = lane & 15;                  // fragment row
    const int ko  = (lane >> 4) << 3;           // fragment k offset in 32-slice
    const int sk0 = (ko)      ^ ((fr & 7) << 3);
    const int sk1 = (32 + ko) ^ ((fr & 7) << 3);
    const int raA = (wm * 64 + fr) * BK;        // + i*1024

    // ---- B direct-from-global per-lane row pointers (L2-served) ----
    const uint16_t* bp0 = B + (size_t)(bn0 + wn * 64 +  0 + fr) * K_DIM + ko;
    const uint16_t* bp1 = B + (size_t)(bn0 + wn * 64 + 16 + fr) * K_DIM + ko;
    const uint16_t* bp2 = B + (size_t)(bn0 + wn * 64 + 32 + fr) * K_DIM + ko;
    const uint16_t* bp3 = B + (size_t)(bn0 + wn * 64 + 48 + fr) * K_DIM + ko;

    floatx4 acc[4][4];
#pragma unroll
    for (int i = 0; i < 4; ++i)
#pragma unroll
        for (int j = 0; j < 4; ++j) acc[i][j] = {0.f, 0.f, 0.f, 0.f};

    short8 bX[4][2], bY[4][2];   // B-frag double buffer (even/odd tiles)

    // ---- prologue: tile0 group (10 VMEM), fence, tile1 group (10 VMEM) ----
    load_lds16(gA0, &lds[ldsA0]);
    load_lds16(gA1, &lds[ldsA1]);
    bX[0][0] = *(const short8*)(bp0);      bX[0][1] = *(const short8*)(bp0 + 32);
    bX[1][0] = *(const short8*)(bp1);      bX[1][1] = *(const short8*)(bp1 + 32);
    bX[2][0] = *(const short8*)(bp2);      bX[2][1] = *(const short8*)(bp2 + 32);
    bX[3][0] = *(const short8*)(bp3);      bX[3][1] = *(const short8*)(bp3 + 32);
    asm volatile("" ::: "memory");         // keep tile0's 10 oldest in the queue
    load_lds16(gA0 + BK, &lds[TILE_A + ldsA0]);
    load_lds16(gA1 + BK, &lds[TILE_A + ldsA1]);
    bY[0][0] = *(const short8*)(bp0 + BK); bY[0][1] = *(const short8*)(bp0 + BK + 32);
    bY[1][0] = *(const short8*)(bp1 + BK); bY[1][1] = *(const short8*)(bp1 + BK + 32);
    bY[2][0] = *(const short8*)(bp2 + BK); bY[2][1] = *(const short8*)(bp2 + BK + 32);
    bY[3][0] = *(const short8*)(bp3 + BK); bY[3][1] = *(const short8*)(bp3 + BK + 32);
    asm volatile("s_waitcnt vmcnt(10)" ::: "memory");   // tile0 landed
    __builtin_amdgcn_s_barrier();

    int cbo = 0;             // compute buffer (tile t)  : buffer t%3
    int sbo = 2 * TILE_A;    // stage buffer (tile t+2)  : buffer (t+2)%3

    for (int t = 0; t < NT; t += 2) {
        GTILE(bX, t, cbo, sbo);
        cbo += TILE_A; if (cbo == 3 * TILE_A) cbo = 0;
        sbo += TILE_A; if (sbo == 3 * TILE_A) sbo = 0;
        GTILE(bY, t + 1, cbo, sbo);
        cbo += TILE_A; if (cbo == 3 * TILE_A) cbo = 0;
        sbo += TILE_A; if (sbo == 3 * TILE_A) sbo = 0;
    }

    // epilogue: C/D layout col=lane&15, row=(lane>>4)*4+reg   [m89/m91]
    const int cn  = lane & 15;
    const int rb4 = (lane >> 4) * 4;
#pragma unroll
    for (int i = 0; i < 4; ++i)
#pragma unroll
        for (int j = 0; j < 4; ++j)
#pragma unroll
            for (int r = 0; r < 4; ++r) {
                const int row = bm0 + wm * 64 + i * 16 + rb4 + r;
                const int col = bn0 + wn * 64 + j * 16 + cn;
                C[(size_t)row * O_FEAT + col] = acc[i][j][r];
            }
}

// ---------------------------------------------------------------------------
extern "C" void kernel_launch(void* const* d_in, const int* in_sizes, int n_in,
                              void* d_out, int out_size, void* d_ws, size_t ws_size,
                              hipStream_t stream) {
    const float* x      = (const float*)d_in[0];
    const void*  packed = d_in[1];
    const float* scales = (const float*)d_in[2];
    const void*  vals   = d_in[3];
    const int*   rows   = (const int*)d_in[4];
    const int*   cols   = (const int*)d_in[5];
    const float* alpha  = (const float*)d_in[6];
    float*       out    = (float*)d_out;
    const int nnz = in_sizes[3];

    uint16_t* W  = (uint16_t*)d_ws;                                        // 32 MB
    uint16_t* Xb = (uint16_t*)((char*)d_ws + (size_t)O_FEAT * I_FEAT * 2); // 16 MB

    // 1) dequant int4 -> bf16 W
    dequant_kernel<<<8192, 256, 0, stream>>>(packed, scales, W);
    // 2) fused: scatter residual into W (blocks < 3328) + x -> bf16 (rest)
    scatter_xconv_kernel<<<SCATTER_BLOCKS + 4096, 256, 0, stream>>>(
        vals, rows, cols, alpha, x, W, Xb, nnz);
    // 3) GEMM: out = Xb (2048x4096) * W^T (4096x4096)
    gemm_bt_kernel<<<dim3(O_FEAT / BN, M_DIM / BM), 512, 0, stream>>>(Xb, W, out);
}

// Round 6
// 227.783 us; speedup vs baseline: 1.8838x; 1.3391x over previous
//
#include <hip/hip_runtime.h>
#include <hip/hip_fp16.h>
#include <stdint.h>

#define O_FEAT 4096
#define I_FEAT 4096
#define M_DIM  2048
#define K_DIM  4096

typedef __attribute__((ext_vector_type(8))) short short8;   // 8 x bf16 (4 VGPRs)
typedef __attribute__((ext_vector_type(2))) short short2v;  // 2 x bf16 (1 VGPR)
typedef __attribute__((ext_vector_type(4))) float floatx4;  // MFMA accumulator

#define AS1 __attribute__((address_space(1)))
#define AS3 __attribute__((address_space(3)))

__device__ __forceinline__ uint16_t f32_to_bf16(float f) {
    uint32_t u = __builtin_bit_cast(uint32_t, f);
    u = (u + 0x7FFFu + ((u >> 16) & 1u)) >> 16;   // round-to-nearest-even
    return (uint16_t)u;
}
__device__ __forceinline__ float bf16_to_f32(uint16_t h) {
    uint32_t u = ((uint32_t)h) << 16;
    return __builtin_bit_cast(float, u);
}

// async global->LDS, 16B per lane; LDS dest = wave-uniform base + lane*16
__device__ __forceinline__ void load_lds16(const uint16_t* gptr, uint16_t* ldsptr) {
    __builtin_amdgcn_global_load_lds((const AS1 uint32_t*)gptr,
                                     (AS3 uint32_t*)ldsptr, 16, 0, 0);
}

// ---------------------------------------------------------------------------
// Kernel 1: dequant int4 -> bf16 W.  (R1-exact)
// ---------------------------------------------------------------------------
__global__ __launch_bounds__(256) void dequant_kernel(
        const void*  __restrict__ packed,
        const float* __restrict__ scales,
        uint16_t*    __restrict__ W) {
    const int lane = threadIdx.x & 63;
    uint32_t probe = ((const uint32_t*)packed)[lane];
    const bool int32mode = (__ballot(probe >= 256u) == 0ull);

    int idx = blockIdx.x * 256 + threadIdx.x;       // 2,097,152 threads
    float s = scales[idx >> 9];                     // 512 byte-quads per row

    uint32_t bytes4;
    if (int32mode) {
        uint4 w = ((const uint4*)packed)[idx];      // 4 int32, each 0..255
        bytes4 = (w.x & 0xFFu) | ((w.y & 0xFFu) << 8) |
                 ((w.z & 0xFFu) << 16) | ((w.w & 0xFFu) << 24);
    } else {
        bytes4 = ((const uint32_t*)packed)[idx];
    }

    uint16_t o[8];
#pragma unroll
    for (int b = 0; b < 4; ++b) {
        int byte = (bytes4 >> (8 * b)) & 0xFF;
        o[2 * b]     = f32_to_bf16((float)((byte & 0xF) - 8) * s);  // low -> even
        o[2 * b + 1] = f32_to_bf16((float)((byte >> 4) - 8) * s);   // high -> odd
    }
    uint4 v;
    v.x = (uint32_t)o[0] | ((uint32_t)o[1] << 16);
    v.y = (uint32_t)o[2] | ((uint32_t)o[3] << 16);
    v.z = (uint32_t)o[4] | ((uint32_t)o[5] << 16);
    v.w = (uint32_t)o[6] | ((uint32_t)o[7] << 16);
    ((uint4*)W)[idx] = v;
}

// ---------------------------------------------------------------------------
// Kernel 2 (fused): scatter COO residual into W (blocks < 3328) + x -> bf16
// (rest).  (R1-exact.)
// ---------------------------------------------------------------------------
#define SCATTER_BLOCKS 3328
__global__ __launch_bounds__(256) void scatter_xconv_kernel(
        const void*  __restrict__ vals,
        const int*   __restrict__ rows,
        const int*   __restrict__ cols,
        const float* __restrict__ alpha,
        const float* __restrict__ x,
        uint16_t*    __restrict__ W,
        uint16_t*    __restrict__ Xb,
        int nnz) {
    if (blockIdx.x < SCATTER_BLOCKS) {
        const int lane = threadIdx.x & 63;
        float p = fabsf(((const float*)vals)[lane]);
        int cnt = __popcll(__ballot(p > 1e-4f && p < 1.0f));
        const bool f32mode = (cnt >= 32);

        int i = blockIdx.x * 256 + threadIdx.x;
        if (i >= nnz) return;
        float v = f32mode ? ((const float*)vals)[i]
                          : __half2float(((const __half*)vals)[i]);
        v *= alpha[0];
        int r = rows[i], c = cols[i];
        size_t elem = (size_t)r * I_FEAT + c;

#if __has_builtin(__builtin_amdgcn_global_atomic_fadd_v2bf16)
        const bool hi = (elem & 1);
        short b = (short)f32_to_bf16(v);
        short2v val;
        val[0] = hi ? (short)0 : b;
        val[1] = hi ? b : (short)0;
        __builtin_amdgcn_global_atomic_fadd_v2bf16(
            (AS1 short2v*)(W + (elem & ~(size_t)1)), val);
#else
        uint32_t* word = (uint32_t*)W + (elem >> 1);
        bool hi = (c & 1);
        uint32_t old = *word, assumed;
        do {
            assumed = old;
            uint16_t cur = hi ? (uint16_t)(assumed >> 16) : (uint16_t)(assumed & 0xFFFF);
            uint16_t nw  = f32_to_bf16(bf16_to_f32(cur) + v);
            uint32_t neww = hi ? ((assumed & 0x0000FFFFu) | ((uint32_t)nw << 16))
                               : ((assumed & 0xFFFF0000u) | (uint32_t)nw);
            old = atomicCAS(word, assumed, neww);
        } while (old != assumed);
#endif
    } else {
        int idx = (blockIdx.x - SCATTER_BLOCKS) * 256 + threadIdx.x;  // 1,048,576
        float4 v0 = ((const float4*)x)[2 * idx];
        float4 v1 = ((const float4*)x)[2 * idx + 1];
        uint4 o;
        o.x = (uint32_t)f32_to_bf16(v0.x) | ((uint32_t)f32_to_bf16(v0.y) << 16);
        o.y = (uint32_t)f32_to_bf16(v0.z) | ((uint32_t)f32_to_bf16(v0.w) << 16);
        o.z = (uint32_t)f32_to_bf16(v1.x) | ((uint32_t)f32_to_bf16(v1.y) << 16);
        o.w = (uint32_t)f32_to_bf16(v1.z) | ((uint32_t)f32_to_bf16(v1.w) << 16);
        ((uint4*)Xb)[idx] = o;
    }
}

// ---------------------------------------------------------------------------
// Kernel 3: C[M,N] = A[M,K] * B[N,K]^T  (bf16 in, fp32 out).
// R13 re-run (R5 bench was a container-level RuntimeError, no kernel verdict;
// code audited: uniform barriers, involution verified, bijective swizzle).
// CROSS-BLOCK OVERLAP: R9's phase-serial model matched 2798 cyc/tile to
// 0.1% — double-barriers serialize reads vs MFMA CU-wide at 1 block/CU.
// Fix: 128x128 tile, 256 thr (4 waves of 64x64 — R9 fragment/swizzle/
// epilogue formulas UNCHANGED), 2-buffer depth-1 prefetch (64 KiB LDS ->
// 2 blocks/CU, grid 512).  Independent blocks dephase (m114).  vmcnt(0)
// only at tile end; sibling block absorbs the drain.
// ---------------------------------------------------------------------------
#define BM 128
#define BN 128
#define BK 64
#define NT (K_DIM / BK)                 // 64
#define BUF_ELEMS 16384                 // A 8192 + B 8192 elems = 32 KiB

#define MFMA16(d, a, b) d = __builtin_amdgcn_mfma_f32_16x16x32_bf16(a, b, d, 0, 0, 0)

__global__ __launch_bounds__(256, 2) void gemm_bt_kernel(
        const uint16_t* __restrict__ A,   // [2048][4096] bf16
        const uint16_t* __restrict__ B,   // [4096][4096] bf16 (row-major [N][K])
        float* __restrict__ C) {          // [2048][4096] fp32
    __shared__ uint16_t lds[2 * BUF_ELEMS];   // 64 KiB, 2 buffers

    const int tid  = threadIdx.x;
    const int wave = tid >> 6;           // 0..3
    const int lane = tid & 63;
    const int wm   = wave >> 1;          // 0..1  (64 rows)
    const int wn   = wave & 1;           // 0..1  (64 cols)

    // XCD-aware bijective block swizzle: 512 blocks, 8 XCDs (512 % 8 == 0)
    const int wgid = blockIdx.y * 32 + blockIdx.x;
    const int swz  = (wgid & 7) * 64 + (wgid >> 3);
    const int bm0  = (swz >> 5) * BM;    // 16 row-tiles
    const int bn0  = (swz & 31) * BN;    // 32 col-tiles

    // ---- staging: each wave stages 32 rows of A and 32 rows of B ----
    // per call: 8 rows x 64 k (1 KiB).  Source pre-swizzled (R9 involution):
    // LDS[r][q] holds global k-quad q^(r&7);  r within chunk = lane>>3.
    const int sr   = lane >> 3;                              // 0..7
    const int xcol = ((lane & 7) ^ sr) << 3;                 // swizzled k-elem
    const uint16_t* gA = A + (size_t)(bm0 + wave * 32 + sr) * K_DIM + xcol;
    const uint16_t* gB = B + (size_t)(bn0 + wave * 32 + sr) * K_DIM + xcol;
    const int ldsA = (wave * 32) * 64;                       // + c*512
    const int ldsB = 8192 + (wave * 32) * 64;                // + c*512

    // ---- LDS read addressing (R9-exact formulas) ----
    const int fr  = lane & 15;                  // fragment row
    const int ko  = (lane >> 4) << 3;           // fragment k offset in 32-slice
    const int sk0 = (ko)      ^ ((fr & 7) << 3);
    const int sk1 = (32 + ko) ^ ((fr & 7) << 3);
    const int raA = (wm * 64 + fr) * BK;                 // + i*1024
    const int raB = 8192 + (wn * 64 + fr) * BK;          // + j*1024

    floatx4 acc[4][4];
#pragma unroll
    for (int i = 0; i < 4; ++i)
#pragma unroll
        for (int j = 0; j < 4; ++j) acc[i][j] = {0.f, 0.f, 0.f, 0.f};

    // ---- prologue: stage tile0 -> buf0 (8 calls/wave), drain, barrier ----
#pragma unroll
    for (int c = 0; c < 4; ++c)
        load_lds16(gA + (size_t)(c * 8) * K_DIM, &lds[ldsA + c * 512]);
#pragma unroll
    for (int c = 0; c < 4; ++c)
        load_lds16(gB + (size_t)(c * 8) * K_DIM, &lds[ldsB + c * 512]);
    asm volatile("s_waitcnt vmcnt(0)" ::: "memory");
    __builtin_amdgcn_s_barrier();

    for (int t = 0; t < NT; ++t) {
        const int cb = (t & 1) * BUF_ELEMS;        // compute buffer
        const int sb = cb ^ BUF_ELEMS;             // stage buffer (tile t+1)
        const bool pf = (t + 1 < NT);
        const size_t kofs = (size_t)(t + 1) * BK;

        // ---- phase 0: read A0,A1,B0,B1 (8); stage A rows 0..23 of t+1 ----
        short8 a00 = *(const short8*)&lds[cb + raA + sk0];
        short8 a01 = *(const short8*)&lds[cb + raA + sk1];
        short8 a10 = *(const short8*)&lds[cb + raA + 1024 + sk0];
        short8 a11 = *(const short8*)&lds[cb + raA + 1024 + sk1];
        short8 b00 = *(const short8*)&lds[cb + raB + sk0];
        short8 b01 = *(const short8*)&lds[cb + raB + sk1];
        short8 b10 = *(const short8*)&lds[cb + raB + 1024 + sk0];
        short8 b11 = *(const short8*)&lds[cb + raB + 1024 + sk1];
        if (pf) {
            load_lds16(gA + kofs,                     &lds[sb + ldsA]);
            load_lds16(gA + kofs + (size_t)8 * K_DIM, &lds[sb + ldsA + 512]);
            load_lds16(gA + kofs + (size_t)16 * K_DIM,&lds[sb + ldsA + 1024]);
        }
        __builtin_amdgcn_s_barrier();
        asm volatile("s_waitcnt lgkmcnt(0)");
        __builtin_amdgcn_s_setprio(1);
        MFMA16(acc[0][0], a00, b00); MFMA16(acc[0][0], a01, b01);
        MFMA16(acc[0][1], a00, b10); MFMA16(acc[0][1], a01, b11);
        MFMA16(acc[1][0], a10, b00); MFMA16(acc[1][0], a11, b01);
        MFMA16(acc[1][1], a10, b10); MFMA16(acc[1][1], a11, b11);
        __builtin_amdgcn_s_setprio(0);
        __builtin_amdgcn_s_barrier();

        // ---- phase 1: read B2,B3 (4); stage A row 24.., B rows 0..15 ----
        short8 b20 = *(const short8*)&lds[cb + raB + 2048 + sk0];
        short8 b21 = *(const short8*)&lds[cb + raB + 2048 + sk1];
        short8 b30 = *(const short8*)&lds[cb + raB + 3072 + sk0];
        short8 b31 = *(const short8*)&lds[cb + raB + 3072 + sk1];
        if (pf) {
            load_lds16(gA + kofs + (size_t)24 * K_DIM,&lds[sb + ldsA + 1536]);
            load_lds16(gB + kofs,                     &lds[sb + ldsB]);
            load_lds16(gB + kofs + (size_t)8 * K_DIM, &lds[sb + ldsB + 512]);
        }
        __builtin_amdgcn_s_barrier();
        asm volatile("s_waitcnt lgkmcnt(0)");
        __builtin_amdgcn_s_setprio(1);
        MFMA16(acc[0][2], a00, b20); MFMA16(acc[0][2], a01, b21);
        MFMA16(acc[0][3], a00, b30); MFMA16(acc[0][3], a01, b31);
        MFMA16(acc[1][2], a10, b20); MFMA16(acc[1][2], a11, b21);
        MFMA16(acc[1][3], a10, b30); MFMA16(acc[1][3], a11, b31);
        __builtin_amdgcn_s_setprio(0);
        __builtin_amdgcn_s_barrier();

        // ---- phase 2: read A2,A3 (4); stage B rows 16..31 ----
        short8 a20 = *(const short8*)&lds[cb + raA + 2048 + sk0];
        short8 a21 = *(const short8*)&lds[cb + raA + 2048 + sk1];
        short8 a30 = *(const short8*)&lds[cb + raA + 3072 + sk0];
        short8 a31 = *(const short8*)&lds[cb + raA + 3072 + sk1];
        if (pf) {
            load_lds16(gB + kofs + (size_t)16 * K_DIM,&lds[sb + ldsB + 1024]);
            load_lds16(gB + kofs + (size_t)24 * K_DIM,&lds[sb + ldsB + 1536]);
        }
        __builtin_amdgcn_s_barrier();
        asm volatile("s_waitcnt lgkmcnt(0)");
        __builtin_amdgcn_s_setprio(1);
        MFMA16(acc[2][2], a20, b20); MFMA16(acc[2][2], a21, b21);
        MFMA16(acc[2][3], a20, b30); MFMA16(acc[2][3], a21, b31);
        MFMA16(acc[3][2], a30, b20); MFMA16(acc[3][2], a31, b21);
        MFMA16(acc[3][3], a30, b30); MFMA16(acc[3][3], a31, b31);
        __builtin_amdgcn_s_setprio(0);
        __builtin_amdgcn_s_barrier();

        // ---- phase 3: reuse regs; drain stage; tile barrier ----
        __builtin_amdgcn_s_setprio(1);
        MFMA16(acc[2][0], a20, b00); MFMA16(acc[2][0], a21, b01);
        MFMA16(acc[2][1], a20, b10); MFMA16(acc[2][1], a21, b11);
        MFMA16(acc[3][0], a30, b00); MFMA16(acc[3][0], a31, b01);
        MFMA16(acc[3][1], a30, b10); MFMA16(acc[3][1], a31, b11);
        __builtin_amdgcn_s_setprio(0);
        if (pf) {
            // tile t+1's 8 loads were issued across phases 0-2 (~2000 cyc
            // ago for the oldest); sibling block covers the residual stall.
            asm volatile("s_waitcnt vmcnt(0)" ::: "memory");
            __builtin_amdgcn_s_barrier();
        }
    }

    // epilogue: C/D layout col=lane&15, row=(lane>>4)*4+reg   [m89/m91]
    const int cn  = lane & 15;
    const int rb4 = (lane >> 4) * 4;
#pragma unroll
    for (int i = 0; i < 4; ++i)
#pragma unroll
        for (int j = 0; j < 4; ++j)
#pragma unroll
            for (int r = 0; r < 4; ++r) {
                const int row = bm0 + wm * 64 + i * 16 + rb4 + r;
                const int col = bn0 + wn * 64 + j * 16 + cn;
                C[(size_t)row * O_FEAT + col] = acc[i][j][r];
            }
}

// ---------------------------------------------------------------------------
extern "C" void kernel_launch(void* const* d_in, const int* in_sizes, int n_in,
                              void* d_out, int out_size, void* d_ws, size_t ws_size,
                              hipStream_t stream) {
    const float* x      = (const float*)d_in[0];
    const void*  packed = d_in[1];
    const float* scales = (const float*)d_in[2];
    const void*  vals   = d_in[3];
    const int*   rows   = (const int*)d_in[4];
    const int*   cols   = (const int*)d_in[5];
    const float* alpha  = (const float*)d_in[6];
    float*       out    = (float*)d_out;
    const int nnz = in_sizes[3];

    uint16_t* W  = (uint16_t*)d_ws;                                        // 32 MB
    uint16_t* Xb = (uint16_t*)((char*)d_ws + (size_t)O_FEAT * I_FEAT * 2); // 16 MB

    // 1) dequant int4 -> bf16 W
    dequant_kernel<<<8192, 256, 0, stream>>>(packed, scales, W);
    // 2) fused: scatter residual into W (blocks < 3328) + x -> bf16 (rest)
    scatter_xconv_kernel<<<SCATTER_BLOCKS + 4096, 256, 0, stream>>>(
        vals, rows, cols, alpha, x, W, Xb, nnz);
    // 3) GEMM: out = Xb (2048x4096) * W^T (4096x4096)
    gemm_bt_kernel<<<dim3(32, 16), 256, 0, stream>>>(Xb, W, out);
}